// Round 9
// baseline (25.204 us; speedup 1.0000x reference)
//
#include <hip/hip_runtime.h>

#define NPTS 524288
#define HID 100
#define PPT 2      // 2 points/thread: 4 waves/SIMD + table-read amortization
#define BLK 256

// s(a) = tanh''-kernel = h^3 - h, h = tanh(a).  Rcp-free evaluation:
//   y = 2*log2(e)*a  (scale folded into table), t = exp2(-|y|) = e^{-2|a|}
//   g ~= 1/(1+t) via degree-5 minimax poly on t in [0,1] (err ~4e-5)
//   h(|a|) = (1-t)*g;  s(|a|) = h*(h^2-1)  (<=0);  s(a) = sign-flip by a's sign
// Per j: 15 VALU + 1 trans (was 8 VALU + 2 trans via exp+rcp inline asm).
// u = Hxy - Hyy accumulates s*ku,  ku = 2*W2*w1y*(w1x - w1y)
// v = Hxy - Hxx accumulates s*kv,  kv = 2*W2*w1x*(w1y - w1x)

__global__ void __launch_bounds__(BLK)
kDivFree_main(const float2* __restrict__ xy,
              const float* __restrict__ W1,
              const float* __restrict__ b1,
              const float* __restrict__ W2,
              float2* __restrict__ out) {
    __shared__ float4 sA[HID];    // cx, cy, cz, ku   (1600 B)
    __shared__ float  sKv[HID];   // kv               (400 B, read as float4)

    int t = threadIdx.x;
    if (t < HID) {
        const float C = 2.8853900817779268f;  // 2*log2(e)
        float w1x = W1[t], w1y = W1[HID + t], w2 = W2[t];
        sA[t] = make_float4(w1x * C, w1y * C, b1[t] * C,
                            2.0f * w2 * w1y * (w1x - w1y));
        sKv[t] = 2.0f * w2 * w1x * (w1y - w1x);
    }
    __syncthreads();

    const float4* sK4 = (const float4*)sKv;

    int base = blockIdx.x * (BLK * PPT) + threadIdx.x;
    float2 p0 = xy[base];
    float2 p1 = xy[base + BLK];
    float u0 = 0.f, v0 = 0.f, u1 = 0.f, v1 = 0.f;

#pragma unroll 5
    for (int j4 = 0; j4 < HID / 4; ++j4) {
        float4 K = sK4[j4];
        float kva[4] = {K.x, K.y, K.z, K.w};
#pragma unroll
        for (int jj = 0; jj < 4; ++jj) {
            float4 A = sA[j4 * 4 + jj];
            float kv = kva[jj];
            {
                float y  = fmaf(p0.x, A.x, fmaf(p0.y, A.y, A.z));
                float tt = __builtin_amdgcn_exp2f(-__builtin_fabsf(y));
                float g  = fmaf(tt, fmaf(tt, fmaf(tt, fmaf(tt, fmaf(tt,
                           -0.10765f, 0.42599f), -0.77778f), 0.95607f),
                           -0.99662f), 0.99996f);
                float h  = fmaf(-tt, g, g);           // tanh(|a|)
                float s  = h * fmaf(h, h, -1.0f);     // s(|a|) <= 0
                s = __int_as_float(__float_as_int(s) ^
                                   (__float_as_int(y) & 0x80000000));
                u0 = fmaf(s, A.w, u0);
                v0 = fmaf(s, kv, v0);
            }
            {
                float y  = fmaf(p1.x, A.x, fmaf(p1.y, A.y, A.z));
                float tt = __builtin_amdgcn_exp2f(-__builtin_fabsf(y));
                float g  = fmaf(tt, fmaf(tt, fmaf(tt, fmaf(tt, fmaf(tt,
                           -0.10765f, 0.42599f), -0.77778f), 0.95607f),
                           -0.99662f), 0.99996f);
                float h  = fmaf(-tt, g, g);
                float s  = h * fmaf(h, h, -1.0f);
                s = __int_as_float(__float_as_int(s) ^
                                   (__float_as_int(y) & 0x80000000));
                u1 = fmaf(s, A.w, u1);
                v1 = fmaf(s, kv, v1);
            }
        }
    }

    out[base]       = make_float2(u0, v0);
    out[base + BLK] = make_float2(u1, v1);
}

extern "C" void kernel_launch(void* const* d_in, const int* in_sizes, int n_in,
                              void* d_out, int out_size, void* d_ws, size_t ws_size,
                              hipStream_t stream) {
    // inputs: 0=f (unused), 1=xy, 2=W1, 3=b1, 4=W2, 5=b2 (unused by Hessian)
    const float* xy = (const float*)d_in[1];
    const float* W1 = (const float*)d_in[2];
    const float* b1 = (const float*)d_in[3];
    const float* W2 = (const float*)d_in[4];

    kDivFree_main<<<NPTS / (BLK * PPT), BLK, 0, stream>>>(
        (const float2*)xy, W1, b1, W2, (float2*)d_out);
}

// Round 10
// 19.725 us; speedup vs baseline: 1.2778x; 1.2778x over previous
//
#include <hip/hip_runtime.h>

#define NPTS 524288
#define HID 100
#define BLK 256
// PPT=2, with the two points packed into <2 x float> lanes so the compiler
// can emit v_pk_fma_f32 (full-rate packed fp32 on gfx950): per j the pair
// costs 8 packed-VALU + 4 trans (exp2,rcp per point) vs 16 scalar + 4.
// Per-SIMD cycle model: pk-VALU 6400 cy ~= trans 6400 cy -> ~2.7us kernel,
// rest of measured time is fixed graph/dispatch overhead (~16-18us, fit
// across R4/R5/R8/R9).

typedef float v2f __attribute__((ext_vector_type(2)));

#if __has_builtin(__builtin_elementwise_fma)
#define VFMA(a, b, c) __builtin_elementwise_fma((a), (b), (c))
#else
#define VFMA(a, b, c) ((a) * (b) + (c))
#endif

// s(a) = h^3 - h, h = tanh(a):  t = e^{2a}, r = 1/(1+t), h = 1-2r.
// u = Hxy - Hyy accumulates s*ku,  ku = 2*W2*w1y*(w1x - w1y)
// v = Hxy - Hxx accumulates s*kv,  kv = 2*W2*w1x*(w1y - w1x)
__global__ void __launch_bounds__(BLK)
kDivFree_main(const float2* __restrict__ xy,
              const float* __restrict__ W1,
              const float* __restrict__ b1,
              const float* __restrict__ W2,
              float2* __restrict__ out) {
    __shared__ float4 sA[HID];    // cx, cy, cz, ku  (scale 2log2e folded)
    __shared__ float  sKv[HID];   // kv

    int t = threadIdx.x;
    if (t < HID) {
        const float C = 2.8853900817779268f;  // 2*log2(e)
        float w1x = W1[t], w1y = W1[HID + t], w2 = W2[t];
        sA[t] = make_float4(w1x * C, w1y * C, b1[t] * C,
                            2.0f * w2 * w1y * (w1x - w1y));
        sKv[t] = 2.0f * w2 * w1x * (w1y - w1x);
    }
    __syncthreads();

    const float4* sK4 = (const float4*)sKv;

    int base = blockIdx.x * (BLK * 2) + threadIdx.x;
    float2 p0 = xy[base];
    float2 p1 = xy[base + BLK];
    v2f px = {p0.x, p1.x};
    v2f py = {p0.y, p1.y};
    v2f u = {0.0f, 0.0f};
    v2f v = {0.0f, 0.0f};
    const v2f one = 1.0f, mtwo = -2.0f, mone = -1.0f;

#pragma unroll 5
    for (int j4 = 0; j4 < HID / 4; ++j4) {
        float4 K = sK4[j4];
        float kva[4] = {K.x, K.y, K.z, K.w};
#pragma unroll
        for (int jj = 0; jj < 4; ++jj) {
            float4 A = sA[j4 * 4 + jj];
            v2f ax = A.x, ay = A.y, az = A.z, ku = A.w, kv = kva[jj];
            v2f y = VFMA(px, ax, VFMA(py, ay, az));   // 2log2e*(x w1x + y w1y + b)
            v2f e;
            e.x = __builtin_amdgcn_exp2f(y.x);        // e^{2a}
            e.y = __builtin_amdgcn_exp2f(y.y);
            v2f d = e + one;
            v2f r;
            r.x = __builtin_amdgcn_rcpf(d.x);         // 1/(1+e^{2a})
            r.y = __builtin_amdgcn_rcpf(d.y);
            v2f h  = VFMA(mtwo, r, one);              // tanh(a)
            v2f hm = VFMA(h, h, mone);                // h^2 - 1
            v2f s  = h * hm;                          // h^3 - h
            u = VFMA(s, ku, u);
            v = VFMA(s, kv, v);
        }
    }

    out[base]       = make_float2(u.x, v.x);
    out[base + BLK] = make_float2(u.y, v.y);
}

extern "C" void kernel_launch(void* const* d_in, const int* in_sizes, int n_in,
                              void* d_out, int out_size, void* d_ws, size_t ws_size,
                              hipStream_t stream) {
    // inputs: 0=f (unused), 1=xy, 2=W1, 3=b1, 4=W2, 5=b2 (unused by Hessian)
    const float* xy = (const float*)d_in[1];
    const float* W1 = (const float*)d_in[2];
    const float* b1 = (const float*)d_in[3];
    const float* W2 = (const float*)d_in[4];

    kDivFree_main<<<NPTS / (BLK * 2), BLK, 0, stream>>>(
        (const float2*)xy, W1, b1, W2, (float2*)d_out);
}